// Round 12
// baseline (410.667 us; speedup 1.0000x reference)
//
#include <hip/hip_runtime.h>
#include <math.h>

#define NN   65536      // total nodes
#define NPG  4096       // nodes per graph
#define NB   16         // graphs
#define NE   524288     // real edges
#define EPG  32768      // edges per graph
#define NH   128        // hidden
#define FN   8          // node feat
#define FE   4          // edge feat
#define NG   16         // global feat
#define NA   10         // actions

// ---------------- fused: degree histogram (blocks < NE/256) + lin1 (rest) ----------------
__global__ void hist_lin1_kernel(const int* __restrict__ ei, int* __restrict__ deg,
                                 const float* __restrict__ x,
                                 const float* __restrict__ Wl, const float* __restrict__ Wr,
                                 float* __restrict__ xl, float* __restrict__ xr) {
    int bid = blockIdx.x;
    if (bid < NE / 256) {
        int e = bid * 256 + threadIdx.x;
        atomicAdd(&deg[ei[NE + e]], 1);
    } else {
        __shared__ float row[2][FN];
        int b2 = bid - NE / 256;
        int sub = threadIdx.x >> 7;
        int k = threadIdx.x & 127;
        int n = b2 * 2 + sub;
        if (k < FN) row[sub][k] = x[n * FN + k];
        __syncthreads();
        float al = 0.f, ar = 0.f;
#pragma unroll
        for (int j = 0; j < FN; ++j) {
            float v = row[sub][j];
            al += v * Wl[j * NH + k];
            ar += v * Wr[j * NH + k];
        }
        xl[n * NH + k] = al;
        xr[n * NH + k] = ar;
    }
}

// ---------------- per-graph exclusive scan of deg -> offs, cursor ----------------
__global__ __launch_bounds__(1024) void scan_kernel(
        const int* __restrict__ deg, int* __restrict__ offs, int* __restrict__ cursor) {
    __shared__ int psum[1024];
    int g = blockIdx.x, t = threadIdx.x;
    int nbase = g * NPG + t * 4;
    int d[4];
    int loc[4];
    int run = 0;
#pragma unroll
    for (int i = 0; i < 4; ++i) { d[i] = deg[nbase + i]; loc[i] = run; run += d[i]; }
    psum[t] = run;
    __syncthreads();
    for (int s = 1; s < 1024; s <<= 1) {
        int add = (t >= s) ? psum[t - s] : 0;
        __syncthreads();
        psum[t] += add;
        __syncthreads();
    }
    int prefix = (t == 0) ? 0 : psum[t - 1];
    int ebase = g * EPG;
#pragma unroll
    for (int i = 0; i < 4; ++i) {
        int v = ebase + prefix + loc[i];
        offs[nbase + i] = v;
        cursor[nbase + i] = v;
    }
    if (g == NB - 1 && t == 0) offs[NN] = NE;
}

// ---------------- CSR fill: packed (src,eid) int2, graph-contiguous ----------------
__global__ void csr_fill_kernel(const int* __restrict__ ei, int* __restrict__ cursor,
                                int2* __restrict__ csr) {
    int e = blockIdx.x * 256 + threadIdx.x;
    int dst = ei[NE + e];
    int pos = atomicAdd(&cursor[dst], 1);
    csr[pos] = make_int2(ei[e], e);
}

// ---------------- GATv2 gather: one 32-lane group per node ----------------
// r11's measured-best loop, deepened: idx prefetch depth 3, DATA prefetch depth 2
// (VGPR headroom 40->~60 stays within the 64-reg / 8-wave budget; covers the ~11%
// first-touch HBM misses the depth-1 pipeline stalled on).
// Templated MODE removes easum/lattr dead code per layer. att pre-scaled by log2e
// -> exp2f. No running-max (scores bounded ~|6|; absmax 0.0 in r4-r11).
// XCD-affine swizzle keeps each graph's xl slice in one XCD's L2.
// MODE 1: relu epilogue, accumulate easum, write lattr.
// MODE 2: read lattr, emit fused mean-pool partials.
template <int MODE>
__global__ __launch_bounds__(256) void gat_gather_kernel(
        const float4* __restrict__ xl, const float4* __restrict__ xr,
        const float4* __restrict__ ea,
        const int2* __restrict__ csr, const int* __restrict__ offs,
        const float* __restrict__ We, const float* __restrict__ att,
        const float* __restrict__ bias, float* __restrict__ out,
        float4* __restrict__ lattr, float4* __restrict__ gpart) {
    __shared__ float4 red[8][32];
    int grp = threadIdx.x >> 5;
    int lane = threadIdx.x & 31;
    int bid = blockIdx.x;
    int xcd = bid & 7, slot = bid >> 3;
    int g = xcd + ((slot >> 9) << 3);   // graphs {xcd, xcd+8}
    int blk = slot & 511;               // block within graph (512 x 8 nodes)
    int node = g * NPG + blk * 8 + grp;

    float4 xr4 = xr[node * 32 + lane];
    float4 att4 = ((const float4*)att)[lane];
    const float LOG2E = 1.44269504f;
    att4.x *= LOG2E; att4.y *= LOG2E; att4.z *= LOG2E; att4.w *= LOG2E;
    const float4* We4 = (const float4*)We;
    float4 we0 = We4[lane];
    float4 we1 = We4[32 + lane];
    float4 we2 = We4[64 + lane];
    float4 we3 = We4[96 + lane];

    int beg = offs[node], end = offs[node + 1];
    float l = 0.f;
    float4 acc = make_float4(0.f, 0.f, 0.f, 0.f);
    float4 easum = make_float4(0.f, 0.f, 0.f, 0.f);
    if (beg < end) {
        int last = end - 1;
        int2 se0 = csr[beg];
        int pa = (beg + 1 <= last) ? beg + 1 : last;
        int pb = (beg + 2 <= last) ? beg + 2 : last;
        int2 se1 = csr[pa];
        int2 se2 = csr[pb];
        float4 xl0 = xl[se0.x * 32 + lane];   // data for p   (depth 2 in steady state)
        float4 a0 = ea[se0.y];
        float4 xl1 = xl[se1.x * 32 + lane];   // data for p+1
        float4 a1 = ea[se1.y];
        for (int p = beg; p < end; ++p) {
            int p3 = (p + 3 <= last) ? p + 3 : last;
            int2 se3 = csr[p3];                       // index prefetch, depth 3
            float4 xl2 = xl[se2.x * 32 + lane];       // data prefetch, depth 2
            float4 a2 = ea[se2.y];
            if (MODE == 1) {
                easum.x += a0.x; easum.y += a0.y; easum.z += a0.z; easum.w += a0.w;
            }
            float tx = xl0.x + xr4.x + a0.x * we0.x + a0.y * we1.x + a0.z * we2.x + a0.w * we3.x;
            float ty = xl0.y + xr4.y + a0.x * we0.y + a0.y * we1.y + a0.z * we2.y + a0.w * we3.y;
            float tz = xl0.z + xr4.z + a0.x * we0.z + a0.y * we1.z + a0.z * we2.z + a0.w * we3.z;
            float tw = xl0.w + xr4.w + a0.x * we0.w + a0.y * we1.w + a0.z * we2.w + a0.w * we3.w;
            tx = fmaxf(tx, 0.2f * tx);
            ty = fmaxf(ty, 0.2f * ty);
            tz = fmaxf(tz, 0.2f * tz);
            tw = fmaxf(tw, 0.2f * tw);
            float s = tx * att4.x + ty * att4.y + tz * att4.z + tw * att4.w;
#pragma unroll
            for (int o = 16; o >= 1; o >>= 1) s += __shfl_xor(s, o);   // stays in 32-group
            float w = exp2f(s);
            l += w;
            acc.x += w * xl0.x;
            acc.y += w * xl0.y;
            acc.z += w * xl0.z;
            acc.w += w * xl0.w;
            se2 = se3;
            xl0 = xl1; a0 = a1;
            xl1 = xl2; a1 = a2;
        }
    }
    // self-loop: src = node, attr = mean incoming ea
    {
        float ax, ay, az, aw;
        if (MODE == 2) {
            float4 la = lattr[node];
            ax = la.x; ay = la.y; az = la.z; aw = la.w;
        } else {
            int deg = end - beg;
            float invd = 1.0f / (float)(deg > 0 ? deg : 1);
            ax = easum.x * invd; ay = easum.y * invd;
            az = easum.z * invd; aw = easum.w * invd;
            if (lane == 0) lattr[node] = make_float4(ax, ay, az, aw);
        }
        float4 xl4 = xl[node * 32 + lane];
        float tx = xl4.x + xr4.x + ax * we0.x + ay * we1.x + az * we2.x + aw * we3.x;
        float ty = xl4.y + xr4.y + ax * we0.y + ay * we1.y + az * we2.y + aw * we3.y;
        float tz = xl4.z + xr4.z + ax * we0.z + ay * we1.z + az * we2.z + aw * we3.z;
        float tw = xl4.w + xr4.w + ax * we0.w + ay * we1.w + az * we2.w + aw * we3.w;
        tx = fmaxf(tx, 0.2f * tx);
        ty = fmaxf(ty, 0.2f * ty);
        tz = fmaxf(tz, 0.2f * tz);
        tw = fmaxf(tw, 0.2f * tw);
        float s = tx * att4.x + ty * att4.y + tz * att4.z + tw * att4.w;
#pragma unroll
        for (int o = 16; o >= 1; o >>= 1) s += __shfl_xor(s, o);
        float w = exp2f(s);
        l += w;
        acc.x += w * xl4.x;
        acc.y += w * xl4.y;
        acc.z += w * xl4.z;
        acc.w += w * xl4.w;
    }
    float inv = 1.0f / l;
    float4 b4 = ((const float4*)bias)[lane];
    float4 o4;
    o4.x = acc.x * inv + b4.x;
    o4.y = acc.y * inv + b4.y;
    o4.z = acc.z * inv + b4.z;
    o4.w = acc.w * inv + b4.w;
    if (MODE == 1) {
        o4.x = fmaxf(o4.x, 0.f); o4.y = fmaxf(o4.y, 0.f);
        o4.z = fmaxf(o4.z, 0.f); o4.w = fmaxf(o4.w, 0.f);
    }
    ((float4*)out)[node * 32 + lane] = o4;

    // fused mean-pool partials: sum o4 over the 8 node-groups of this block
    if (MODE == 2) {
        red[grp][lane] = o4;
        __syncthreads();
        if (grp < 4) {
            float4 o = red[grp + 4][lane];
            red[grp][lane] = make_float4(red[grp][lane].x + o.x, red[grp][lane].y + o.y,
                                         red[grp][lane].z + o.z, red[grp][lane].w + o.w);
        }
        __syncthreads();
        if (grp < 2) {
            float4 o = red[grp + 2][lane];
            red[grp][lane] = make_float4(red[grp][lane].x + o.x, red[grp][lane].y + o.y,
                                         red[grp][lane].z + o.z, red[grp][lane].w + o.w);
        }
        __syncthreads();
        if (grp == 0) {
            float4 a = red[0][lane], b = red[1][lane];
            gpart[(g * 512 + blk) * 32 + lane] =
                make_float4(a.x + b.x, a.y + b.y, a.z + b.z, a.w + b.w);
        }
    }
}

// ---------------- layer-2 projections: 64x64 tile, BOTH matrices per block ----------------
#define FMA4(accv, s, bv) do { accv.x += (s) * (bv).x; accv.y += (s) * (bv).y; \
                               accv.z += (s) * (bv).z; accv.w += (s) * (bv).w; } while (0)
__global__ __launch_bounds__(256) void lin2_gemm_kernel(
        const float* __restrict__ A, const float* __restrict__ Wl2,
        const float* __restrict__ Wr2, float* __restrict__ xl, float* __restrict__ xr) {
    __shared__ __align__(16) float As[64][20];
    __shared__ __align__(16) float Bl[16][64];
    __shared__ __align__(16) float Br[16][64];
    int rowBase = blockIdx.x * 64;
    int colBase = blockIdx.y * 64;
    int t = threadIdx.x;
    int tx = t & 15, ty = t >> 4;
    int ar = t >> 2, aq = (t & 3) * 4;
    int brow = t >> 4, bcol = (t & 15) * 4;
    float4 accL[4] = {};
    float4 accR[4] = {};
    for (int kk = 0; kk < NH; kk += 16) {
        float4 av = *(const float4*)&A[(size_t)(rowBase + ar) * NH + kk + aq];
        float4 blv = *(const float4*)&Wl2[(size_t)(kk + brow) * NH + colBase + bcol];
        float4 brv = *(const float4*)&Wr2[(size_t)(kk + brow) * NH + colBase + bcol];
        __syncthreads();
        *(float4*)&As[ar][aq] = av;
        *(float4*)&Bl[brow][bcol] = blv;
        *(float4*)&Br[brow][bcol] = brv;
        __syncthreads();
#pragma unroll
        for (int c4 = 0; c4 < 4; ++c4) {
            float4 a4[4], bl4[4], br4[4];
#pragma unroll
            for (int i = 0; i < 4; ++i) a4[i] = *(const float4*)&As[ty * 4 + i][c4 * 4];
#pragma unroll
            for (int j = 0; j < 4; ++j) {
                bl4[j] = *(const float4*)&Bl[c4 * 4 + j][tx * 4];
                br4[j] = *(const float4*)&Br[c4 * 4 + j][tx * 4];
            }
#pragma unroll
            for (int i = 0; i < 4; ++i) {
                FMA4(accL[i], a4[i].x, bl4[0]);
                FMA4(accL[i], a4[i].y, bl4[1]);
                FMA4(accL[i], a4[i].z, bl4[2]);
                FMA4(accL[i], a4[i].w, bl4[3]);
                FMA4(accR[i], a4[i].x, br4[0]);
                FMA4(accR[i], a4[i].y, br4[1]);
                FMA4(accR[i], a4[i].z, br4[2]);
                FMA4(accR[i], a4[i].w, br4[3]);
            }
        }
    }
#pragma unroll
    for (int i = 0; i < 4; ++i) {
        size_t off = (size_t)(rowBase + ty * 4 + i) * NH + colBase + tx * 4;
        *(float4*)&xl[off] = accL[i];
        *(float4*)&xr[off] = accR[i];
    }
}

// ---------------- head MLP: one block per graph (sums fused-pool partials) ----------------
__global__ void head_kernel(const float* __restrict__ gpart, const float* __restrict__ h,
                            const float* __restrict__ gstate, const int* __restrict__ cpn,
                            const float* __restrict__ Wc, const float* __restrict__ bc,
                            const float* __restrict__ Wa1, const float* __restrict__ ba1,
                            const float* __restrict__ Wa2, const float* __restrict__ ba2,
                            const float* __restrict__ Wv1, const float* __restrict__ bv1,
                            const float* __restrict__ Wv2, const float* __restrict__ bv2,
                            float* __restrict__ out) {
    int b = blockIdx.x, t = threadIdx.x;
    __shared__ float comb[400];
    __shared__ float feat[256];
    __shared__ float hid[256];
    int n0 = cpn[b * 2 + 0] + b * NPG;
    int n1 = cpn[b * 2 + 1] + b * NPG;
    if (t < 128) {
        float s0 = 0.f, s1 = 0.f, s2 = 0.f, s3 = 0.f;
        const float* gp = gpart + (size_t)b * 512 * NH + t;
        for (int c = 0; c < 512; c += 4) {
            s0 += gp[(c + 0) * NH];
            s1 += gp[(c + 1) * NH];
            s2 += gp[(c + 2) * NH];
            s3 += gp[(c + 3) * NH];
        }
        comb[t] = (s0 + s1 + s2 + s3) * (1.0f / NPG);
        comb[128 + t] = h[n0 * NH + t];
    } else {
        int tt = t - 128;
        comb[256 + tt] = h[n1 * NH + tt];
        if (tt < NG) comb[384 + tt] = gstate[b * NG + tt];
    }
    __syncthreads();
    float acc = bc[t];
    for (int j = 0; j < 400; ++j) acc += comb[j] * Wc[j * 256 + t];
    feat[t] = fmaxf(acc, 0.f);
    __syncthreads();
    if (t < 128) {
        float a2 = ba1[t];
        for (int j = 0; j < 256; ++j) a2 += feat[j] * Wa1[j * NH + t];
        hid[t] = fmaxf(a2, 0.f);
    } else {
        int tt = t - 128;
        float a2 = bv1[tt];
        for (int j = 0; j < 256; ++j) a2 += feat[j] * Wv1[j * NH + tt];
        hid[128 + tt] = fmaxf(a2, 0.f);
    }
    __syncthreads();
    if (t < NA) {
        float a2 = ba2[t];
        for (int j = 0; j < NH; ++j) a2 += hid[j] * Wa2[j * NA + t];
        out[b * 11 + t] = a2;
    } else if (t == NA) {
        float a2 = bv2[0];
        for (int j = 0; j < NH; ++j) a2 += hid[128 + j] * Wv2[j];
        out[b * 11 + 10] = a2;
    }
}

extern "C" void kernel_launch(void* const* d_in, const int* in_sizes, int n_in,
                              void* d_out, int out_size, void* d_ws, size_t ws_size,
                              hipStream_t stream) {
    const float* x      = (const float*)d_in[0];
    const int*   ei     = (const int*)d_in[1];
    const float* ea     = (const float*)d_in[2];
    const float* gstate = (const float*)d_in[3];
    const int*   cpn    = (const int*)d_in[4];
    const float* Wl1 = (const float*)d_in[5];
    const float* Wr1 = (const float*)d_in[6];
    const float* We1 = (const float*)d_in[7];
    const float* att1= (const float*)d_in[8];
    const float* b1  = (const float*)d_in[9];
    const float* Wl2 = (const float*)d_in[10];
    const float* Wr2 = (const float*)d_in[11];
    const float* We2 = (const float*)d_in[12];
    const float* att2= (const float*)d_in[13];
    const float* b2  = (const float*)d_in[14];
    const float* Wc  = (const float*)d_in[15];
    const float* bc  = (const float*)d_in[16];
    const float* Wa1 = (const float*)d_in[17];
    const float* ba1 = (const float*)d_in[18];
    const float* Wa2 = (const float*)d_in[19];
    const float* ba2 = (const float*)d_in[20];
    const float* Wv1 = (const float*)d_in[21];
    const float* bv1 = (const float*)d_in[22];
    const float* Wv2 = (const float*)d_in[23];
    const float* bv2 = (const float*)d_in[24];

    char* ws = (char*)d_ws;
    size_t o = 0;
    float* xl    = (float*)(ws + o); o += (size_t)NN * NH * 4;   // 32 MB
    float* xr    = (float*)(ws + o); o += (size_t)NN * NH * 4;   // 32 MB
    float* h     = (float*)(ws + o); o += (size_t)NN * NH * 4;   // 32 MB
    float* lattr = (float*)(ws + o); o += (size_t)NN * 16;       // 1 MB
    float* gpart = (float*)(ws + o); o += (size_t)NB * 512 * NH * 4;  // 4 MB
    int*   offs  = (int*)(ws + o);   o += (((size_t)(NN + 1) * 4 + 255) & ~(size_t)255);
    int*   cursor= (int*)(ws + o);   o += (size_t)NN * 4;
    int*   deg   = (int*)(ws + o);   o += (size_t)NN * 4;
    int2*  csr   = (int2*)(ws + o);  o += (size_t)NE * 8;        // 4 MB
    (void)o; (void)ws_size; (void)in_sizes; (void)n_in; (void)out_size;

    hipMemsetAsync(deg, 0, (size_t)NN * 4, stream);
    hist_lin1_kernel<<<NE / 256 + NN / 2, 256, 0, stream>>>(ei, deg, x, Wl1, Wr1, xl, xr);
    scan_kernel<<<NB, 1024, 0, stream>>>(deg, offs, cursor);
    csr_fill_kernel<<<NE / 256, 256, 0, stream>>>(ei, cursor, csr);
    gat_gather_kernel<1><<<NN / 8, 256, 0, stream>>>((const float4*)xl, (const float4*)xr,
        (const float4*)ea, csr, offs, We1, att1, b1, h, (float4*)lattr, nullptr);
    lin2_gemm_kernel<<<dim3(NN / 64, 2), 256, 0, stream>>>(h, Wl2, Wr2, xl, xr);
    gat_gather_kernel<2><<<NN / 8, 256, 0, stream>>>((const float4*)xl, (const float4*)xr,
        (const float4*)ea, csr, offs, We2, att2, b2, h, (float4*)lattr, (float4*)gpart);
    head_kernel<<<NB, 256, 0, stream>>>(gpart, h, gstate, cpn, Wc, bc, Wa1, ba1, Wa2, ba2,
                                        Wv1, bv1, Wv2, bv2, (float*)d_out);
}

// Round 13
// 347.758 us; speedup vs baseline: 1.1809x; 1.1809x over previous
//
#include <hip/hip_runtime.h>
#include <math.h>

#define NN   65536      // total nodes
#define NPG  4096       // nodes per graph
#define NB   16         // graphs
#define NE   524288     // real edges
#define EPG  32768      // edges per graph
#define NH   128        // hidden
#define FN   8          // node feat
#define FE   4          // edge feat
#define NG   16         // global feat
#define NA   10         // actions

typedef __attribute__((ext_vector_type(8))) short bf16x8;
typedef __attribute__((ext_vector_type(4))) float f32x4;

static __device__ __forceinline__ short bf16rne(float f) {
    unsigned u = __builtin_bit_cast(unsigned, f);
    u += 0x7FFFu + ((u >> 16) & 1u);
    return (short)(u >> 16);
}

// ---------------- fused: degree histogram (blocks < NE/256) + lin1 (rest) ----------------
__global__ void hist_lin1_kernel(const int* __restrict__ ei, int* __restrict__ deg,
                                 const float* __restrict__ x,
                                 const float* __restrict__ Wl, const float* __restrict__ Wr,
                                 float* __restrict__ xl, float* __restrict__ xr) {
    int bid = blockIdx.x;
    if (bid < NE / 256) {
        int e = bid * 256 + threadIdx.x;
        atomicAdd(&deg[ei[NE + e]], 1);
    } else {
        __shared__ float row[2][FN];
        int b2 = bid - NE / 256;
        int sub = threadIdx.x >> 7;
        int k = threadIdx.x & 127;
        int n = b2 * 2 + sub;
        if (k < FN) row[sub][k] = x[n * FN + k];
        __syncthreads();
        float al = 0.f, ar = 0.f;
#pragma unroll
        for (int j = 0; j < FN; ++j) {
            float v = row[sub][j];
            al += v * Wl[j * NH + k];
            ar += v * Wr[j * NH + k];
        }
        xl[n * NH + k] = al;
        xr[n * NH + k] = ar;
    }
}

// ---------------- per-graph exclusive scan of deg -> offs, cursor ----------------
__global__ __launch_bounds__(1024) void scan_kernel(
        const int* __restrict__ deg, int* __restrict__ offs, int* __restrict__ cursor) {
    __shared__ int psum[1024];
    int g = blockIdx.x, t = threadIdx.x;
    int nbase = g * NPG + t * 4;
    int d[4];
    int loc[4];
    int run = 0;
#pragma unroll
    for (int i = 0; i < 4; ++i) { d[i] = deg[nbase + i]; loc[i] = run; run += d[i]; }
    psum[t] = run;
    __syncthreads();
    for (int s = 1; s < 1024; s <<= 1) {
        int add = (t >= s) ? psum[t - s] : 0;
        __syncthreads();
        psum[t] += add;
        __syncthreads();
    }
    int prefix = (t == 0) ? 0 : psum[t - 1];
    int ebase = g * EPG;
#pragma unroll
    for (int i = 0; i < 4; ++i) {
        int v = ebase + prefix + loc[i];
        offs[nbase + i] = v;
        cursor[nbase + i] = v;
    }
    if (g == NB - 1 && t == 0) offs[NN] = NE;
}

// ---------------- CSR fill: packed (src,eid) int2, graph-contiguous ----------------
__global__ void csr_fill_kernel(const int* __restrict__ ei, int* __restrict__ cursor,
                                int2* __restrict__ csr) {
    int e = blockIdx.x * 256 + threadIdx.x;
    int dst = ei[NE + e];
    int pos = atomicAdd(&cursor[dst], 1);
    csr[pos] = make_int2(ei[e], e);
}

// ---------------- GATv2 gather: one 32-lane group per node (measured-best r11 config) ----------------
// DO NOT restructure: contiguous CSR + depth-2 idx / depth-1 data prefetch + __expf
// + runtime flags is the measured optimum (60us); 5 structural variants all regressed
// (r7 +9, r8 +54, r9 +31, r10 +50, r12 +20).
__global__ __launch_bounds__(256) void gat_gather_kernel(
        const float4* __restrict__ xl, const float4* __restrict__ xr,
        const float4* __restrict__ ea,
        const int2* __restrict__ csr, const int* __restrict__ offs,
        const float* __restrict__ We, const float* __restrict__ att,
        const float* __restrict__ bias, float* __restrict__ out,
        float4* __restrict__ lattr_w, const float4* __restrict__ lattr_r,
        float4* __restrict__ gpart, int do_relu) {
    __shared__ float4 red[8][32];
    int grp = threadIdx.x >> 5;
    int lane = threadIdx.x & 31;
    int bid = blockIdx.x;
    int xcd = bid & 7, slot = bid >> 3;
    int g = xcd + ((slot >> 9) << 3);   // graphs {xcd, xcd+8}
    int blk = slot & 511;               // block within graph (512 x 8 nodes)
    int node = g * NPG + blk * 8 + grp;

    float4 xr4 = xr[node * 32 + lane];
    float4 att4 = ((const float4*)att)[lane];
    const float4* We4 = (const float4*)We;
    float4 we0 = We4[lane];
    float4 we1 = We4[32 + lane];
    float4 we2 = We4[64 + lane];
    float4 we3 = We4[96 + lane];

    int beg = offs[node], end = offs[node + 1];
    float l = 0.f;
    float4 acc = make_float4(0.f, 0.f, 0.f, 0.f);
    float4 easum = make_float4(0.f, 0.f, 0.f, 0.f);
    bool have_lattr = (lattr_r != nullptr);
    if (beg < end) {
        int last = end - 1;
        int2 se0 = csr[beg];
        int p1 = (beg + 1 <= last) ? beg + 1 : last;
        int2 se1 = csr[p1];
        float4 xl0 = xl[se0.x * 32 + lane];
        float4 a0 = ea[se0.y];
        for (int p = beg; p < end; ++p) {
            int p2 = (p + 2 <= last) ? p + 2 : last;
            int2 se2 = csr[p2];                       // index prefetch, depth 2
            float4 xl1 = xl[se1.x * 32 + lane];       // data prefetch, depth 1
            float4 a1 = ea[se1.y];
            if (!have_lattr) {
                easum.x += a0.x; easum.y += a0.y; easum.z += a0.z; easum.w += a0.w;
            }
            float tx = xl0.x + xr4.x + a0.x * we0.x + a0.y * we1.x + a0.z * we2.x + a0.w * we3.x;
            float ty = xl0.y + xr4.y + a0.x * we0.y + a0.y * we1.y + a0.z * we2.y + a0.w * we3.y;
            float tz = xl0.z + xr4.z + a0.x * we0.z + a0.y * we1.z + a0.z * we2.z + a0.w * we3.z;
            float tw = xl0.w + xr4.w + a0.x * we0.w + a0.y * we1.w + a0.z * we2.w + a0.w * we3.w;
            tx = tx > 0.f ? tx : 0.2f * tx;
            ty = ty > 0.f ? ty : 0.2f * ty;
            tz = tz > 0.f ? tz : 0.2f * tz;
            tw = tw > 0.f ? tw : 0.2f * tw;
            float s = tx * att4.x + ty * att4.y + tz * att4.z + tw * att4.w;
#pragma unroll
            for (int o = 16; o >= 1; o >>= 1) s += __shfl_xor(s, o);   // stays in 32-group
            float w = __expf(s);
            l += w;
            acc.x += w * xl0.x;
            acc.y += w * xl0.y;
            acc.z += w * xl0.z;
            acc.w += w * xl0.w;
            se1 = se2; xl0 = xl1; a0 = a1;
        }
    }
    // self-loop: src = node, attr = mean incoming ea
    {
        float ax, ay, az, aw;
        if (have_lattr) {
            float4 la = lattr_r[node];
            ax = la.x; ay = la.y; az = la.z; aw = la.w;
        } else {
            int deg = end - beg;
            float invd = 1.0f / (float)(deg > 0 ? deg : 1);
            ax = easum.x * invd; ay = easum.y * invd;
            az = easum.z * invd; aw = easum.w * invd;
            if (lane == 0) lattr_w[node] = make_float4(ax, ay, az, aw);
        }
        float4 xl4 = xl[node * 32 + lane];
        float tx = xl4.x + xr4.x + ax * we0.x + ay * we1.x + az * we2.x + aw * we3.x;
        float ty = xl4.y + xr4.y + ax * we0.y + ay * we1.y + az * we2.y + aw * we3.y;
        float tz = xl4.z + xr4.z + ax * we0.z + ay * we1.z + az * we2.z + aw * we3.z;
        float tw = xl4.w + xr4.w + ax * we0.w + ay * we1.w + az * we2.w + aw * we3.w;
        tx = tx > 0.f ? tx : 0.2f * tx;
        ty = ty > 0.f ? ty : 0.2f * ty;
        tz = tz > 0.f ? tz : 0.2f * tz;
        tw = tw > 0.f ? tw : 0.2f * tw;
        float s = tx * att4.x + ty * att4.y + tz * att4.z + tw * att4.w;
#pragma unroll
        for (int o = 16; o >= 1; o >>= 1) s += __shfl_xor(s, o);
        float w = __expf(s);
        l += w;
        acc.x += w * xl4.x;
        acc.y += w * xl4.y;
        acc.z += w * xl4.z;
        acc.w += w * xl4.w;
    }
    float inv = 1.0f / l;
    float4 b4 = ((const float4*)bias)[lane];
    float4 o4;
    o4.x = acc.x * inv + b4.x;
    o4.y = acc.y * inv + b4.y;
    o4.z = acc.z * inv + b4.z;
    o4.w = acc.w * inv + b4.w;
    if (do_relu) {
        o4.x = fmaxf(o4.x, 0.f); o4.y = fmaxf(o4.y, 0.f);
        o4.z = fmaxf(o4.z, 0.f); o4.w = fmaxf(o4.w, 0.f);
    }
    ((float4*)out)[node * 32 + lane] = o4;

    // fused mean-pool partials: sum o4 over the 8 node-groups of this block
    if (gpart != nullptr) {
        red[grp][lane] = o4;
        __syncthreads();
        if (grp < 4) {
            float4 o = red[grp + 4][lane];
            red[grp][lane] = make_float4(red[grp][lane].x + o.x, red[grp][lane].y + o.y,
                                         red[grp][lane].z + o.z, red[grp][lane].w + o.w);
        }
        __syncthreads();
        if (grp < 2) {
            float4 o = red[grp + 2][lane];
            red[grp][lane] = make_float4(red[grp][lane].x + o.x, red[grp][lane].y + o.y,
                                         red[grp][lane].z + o.z, red[grp][lane].w + o.w);
        }
        __syncthreads();
        if (grp == 0) {
            float4 a = red[0][lane], b = red[1][lane];
            gpart[(g * 512 + blk) * 32 + lane] =
                make_float4(a.x + b.x, a.y + b.y, a.z + b.z, a.w + b.w);
        }
    }
}

// ---------------- layer-2 projections: bf16 MFMA (fp32 accumulate) ----------------
// grid (NN/64, 2): y selects Wl2->xl / Wr2->xr. Block = 4 waves; wave w computes
// rows [rowBase+16w, +16) x all 128 cols via 16x16x32 bf16 MFMA (K=128 -> 4 mfma/tile).
// W staged in LDS as B-fragments (bf16, ds_read_b128-contiguous per lane).
// Layouts (HW-verified): A[m=lane&15][k=(lane>>4)*8+j] (m120);
// C/D col=lane&15, row=(lane>>4)*4+reg (m89).
__global__ __launch_bounds__(256) void lin2_mfma_kernel(
        const float* __restrict__ A, const float* __restrict__ Wl2,
        const float* __restrict__ Wr2, float* __restrict__ xl, float* __restrict__ xr) {
    __shared__ short bfrag[8 * 4 * 64 * 8];   // [ct][kg][lane][j] bf16 = 32 KB
    const float* W = blockIdx.y ? Wr2 : Wl2;
    float* C = blockIdx.y ? xr : xl;
    int t = threadIdx.x;
    // stage W -> B fragments
    {
        int k = t >> 1;
        int c0 = (t & 1) * 64;
        int kg = k >> 5, ko = k & 31;
        int laneHi = (ko >> 3) << 4, j = ko & 7;
        const float4* Wrow = (const float4*)&W[k * NH + c0];
#pragma unroll
        for (int q = 0; q < 16; ++q) {
            float4 v = Wrow[q];
            float vals[4] = {v.x, v.y, v.z, v.w};
            int col = c0 + q * 4;
#pragma unroll
            for (int i = 0; i < 4; ++i) {
                int cc = col + i;
                int ct = cc >> 4;
                int lane = laneHi | (cc & 15);
                bfrag[(((ct << 2) | kg) * 64 + lane) * 8 + j] = bf16rne(vals[i]);
            }
        }
    }
    __syncthreads();
    int wv = t >> 6, lane = t & 63;
    int row0 = blockIdx.x * 64 + wv * 16;
    int m = lane & 15, qd = lane >> 4;
    // A fragments: lane holds A[row0+m][kg*32 + qd*8 + j], j=0..7
    bf16x8 afrag[4];
    const float* Arow = &A[(size_t)(row0 + m) * NH + qd * 8];
#pragma unroll
    for (int kg = 0; kg < 4; ++kg) {
        float4 v0 = *(const float4*)&Arow[kg * 32];
        float4 v1 = *(const float4*)&Arow[kg * 32 + 4];
        afrag[kg][0] = bf16rne(v0.x); afrag[kg][1] = bf16rne(v0.y);
        afrag[kg][2] = bf16rne(v0.z); afrag[kg][3] = bf16rne(v0.w);
        afrag[kg][4] = bf16rne(v1.x); afrag[kg][5] = bf16rne(v1.y);
        afrag[kg][6] = bf16rne(v1.z); afrag[kg][7] = bf16rne(v1.w);
    }
    const bf16x8* bf8 = (const bf16x8*)bfrag;
#pragma unroll
    for (int ct = 0; ct < 8; ++ct) {
        f32x4 acc = {0.f, 0.f, 0.f, 0.f};
#pragma unroll
        for (int kg = 0; kg < 4; ++kg) {
            bf16x8 b = bf8[((ct << 2) | kg) * 64 + lane];
            acc = __builtin_amdgcn_mfma_f32_16x16x32_bf16(afrag[kg], b, acc, 0, 0, 0);
        }
        int col = ct * 16 + m;
#pragma unroll
        for (int r = 0; r < 4; ++r)
            C[(size_t)(row0 + qd * 4 + r) * NH + col] = acc[r];
    }
}

// ---------------- head MLP: one block per graph (sums fused-pool partials) ----------------
__global__ void head_kernel(const float* __restrict__ gpart, const float* __restrict__ h,
                            const float* __restrict__ gstate, const int* __restrict__ cpn,
                            const float* __restrict__ Wc, const float* __restrict__ bc,
                            const float* __restrict__ Wa1, const float* __restrict__ ba1,
                            const float* __restrict__ Wa2, const float* __restrict__ ba2,
                            const float* __restrict__ Wv1, const float* __restrict__ bv1,
                            const float* __restrict__ Wv2, const float* __restrict__ bv2,
                            float* __restrict__ out) {
    int b = blockIdx.x, t = threadIdx.x;
    __shared__ float comb[400];
    __shared__ float feat[256];
    __shared__ float hid[256];
    int n0 = cpn[b * 2 + 0] + b * NPG;
    int n1 = cpn[b * 2 + 1] + b * NPG;
    if (t < 128) {
        float s0 = 0.f, s1 = 0.f, s2 = 0.f, s3 = 0.f;
        const float* gp = gpart + (size_t)b * 512 * NH + t;
        for (int c = 0; c < 512; c += 4) {
            s0 += gp[(c + 0) * NH];
            s1 += gp[(c + 1) * NH];
            s2 += gp[(c + 2) * NH];
            s3 += gp[(c + 3) * NH];
        }
        comb[t] = (s0 + s1 + s2 + s3) * (1.0f / NPG);
        comb[128 + t] = h[n0 * NH + t];
    } else {
        int tt = t - 128;
        comb[256 + tt] = h[n1 * NH + tt];
        if (tt < NG) comb[384 + tt] = gstate[b * NG + tt];
    }
    __syncthreads();
    float acc = bc[t];
    for (int j = 0; j < 400; ++j) acc += comb[j] * Wc[j * 256 + t];
    feat[t] = fmaxf(acc, 0.f);
    __syncthreads();
    if (t < 128) {
        float a2 = ba1[t];
        for (int j = 0; j < 256; ++j) a2 += feat[j] * Wa1[j * NH + t];
        hid[t] = fmaxf(a2, 0.f);
    } else {
        int tt = t - 128;
        float a2 = bv1[tt];
        for (int j = 0; j < 256; ++j) a2 += feat[j] * Wv1[j * NH + tt];
        hid[128 + tt] = fmaxf(a2, 0.f);
    }
    __syncthreads();
    if (t < NA) {
        float a2 = ba2[t];
        for (int j = 0; j < NH; ++j) a2 += hid[j] * Wa2[j * NA + t];
        out[b * 11 + t] = a2;
    } else if (t == NA) {
        float a2 = bv2[0];
        for (int j = 0; j < NH; ++j) a2 += hid[128 + j] * Wv2[j];
        out[b * 11 + 10] = a2;
    }
}

extern "C" void kernel_launch(void* const* d_in, const int* in_sizes, int n_in,
                              void* d_out, int out_size, void* d_ws, size_t ws_size,
                              hipStream_t stream) {
    const float* x      = (const float*)d_in[0];
    const int*   ei     = (const int*)d_in[1];
    const float* ea     = (const float*)d_in[2];
    const float* gstate = (const float*)d_in[3];
    const int*   cpn    = (const int*)d_in[4];
    const float* Wl1 = (const float*)d_in[5];
    const float* Wr1 = (const float*)d_in[6];
    const float* We1 = (const float*)d_in[7];
    const float* att1= (const float*)d_in[8];
    const float* b1  = (const float*)d_in[9];
    const float* Wl2 = (const float*)d_in[10];
    const float* Wr2 = (const float*)d_in[11];
    const float* We2 = (const float*)d_in[12];
    const float* att2= (const float*)d_in[13];
    const float* b2  = (const float*)d_in[14];
    const float* Wc  = (const float*)d_in[15];
    const float* bc  = (const float*)d_in[16];
    const float* Wa1 = (const float*)d_in[17];
    const float* ba1 = (const float*)d_in[18];
    const float* Wa2 = (const float*)d_in[19];
    const float* ba2 = (const float*)d_in[20];
    const float* Wv1 = (const float*)d_in[21];
    const float* bv1 = (const float*)d_in[22];
    const float* Wv2 = (const float*)d_in[23];
    const float* bv2 = (const float*)d_in[24];

    char* ws = (char*)d_ws;
    size_t o = 0;
    float* xl    = (float*)(ws + o); o += (size_t)NN * NH * 4;   // 32 MB
    float* xr    = (float*)(ws + o); o += (size_t)NN * NH * 4;   // 32 MB
    float* h     = (float*)(ws + o); o += (size_t)NN * NH * 4;   // 32 MB
    float* lattr = (float*)(ws + o); o += (size_t)NN * 16;       // 1 MB
    float* gpart = (float*)(ws + o); o += (size_t)NB * 512 * NH * 4;  // 4 MB
    int*   offs  = (int*)(ws + o);   o += (((size_t)(NN + 1) * 4 + 255) & ~(size_t)255);
    int*   cursor= (int*)(ws + o);   o += (size_t)NN * 4;
    int*   deg   = (int*)(ws + o);   o += (size_t)NN * 4;
    int2*  csr   = (int2*)(ws + o);  o += (size_t)NE * 8;        // 4 MB
    (void)o; (void)ws_size; (void)in_sizes; (void)n_in; (void)out_size;

    hipMemsetAsync(deg, 0, (size_t)NN * 4, stream);
    hist_lin1_kernel<<<NE / 256 + NN / 2, 256, 0, stream>>>(ei, deg, x, Wl1, Wr1, xl, xr);
    scan_kernel<<<NB, 1024, 0, stream>>>(deg, offs, cursor);
    csr_fill_kernel<<<NE / 256, 256, 0, stream>>>(ei, cursor, csr);
    gat_gather_kernel<<<NN / 8, 256, 0, stream>>>((const float4*)xl, (const float4*)xr,
        (const float4*)ea, csr, offs, We1, att1, b1, h, (float4*)lattr, nullptr, nullptr, 1);
    lin2_mfma_kernel<<<dim3(NN / 64, 2), 256, 0, stream>>>(h, Wl2, Wr2, xl, xr);
    gat_gather_kernel<<<NN / 8, 256, 0, stream>>>((const float4*)xl, (const float4*)xr,
        (const float4*)ea, csr, offs, We2, att2, b2, h, nullptr, (const float4*)lattr,
        (float4*)gpart, 0);
    head_kernel<<<NB, 256, 0, stream>>>(gpart, h, gstate, cpn, Wc, bc, Wa1, ba1, Wa2, ba2,
                                        Wv1, bv1, Wv2, bv2, (float*)d_out);
}